// Round 7
// baseline (297.709 us; speedup 1.0000x reference)
//
#include <hip/hip_runtime.h>
#include <math.h>

#define BDIM 16
#define LDIM 512
#define CDIM 1024
#define NH 8
#define HD 128
#define MROWS (BDIM * LDIM)   /* 8192 */
#define N3 (3 * CDIM)         /* 3072 */

typedef unsigned short u16;
typedef unsigned long long u64;
typedef short s8v __attribute__((ext_vector_type(8)));   // 8 bf16 = 4 VGPRs (MFMA A/B frag)
typedef short s4v __attribute__((ext_vector_type(4)));   // 4 bf16 = 2 VGPRs
typedef float f32x4 __attribute__((ext_vector_type(4))); // MFMA C/D frag

__device__ __forceinline__ float sigmoidf_(float z) {
    return 1.0f / (1.0f + __expf(-z));
}
__device__ __forceinline__ u16 f2bf(float f) {
    union { float f; unsigned int u; } v; v.f = f;
    unsigned int u = v.u;
    unsigned int r = (u + 0x7FFFu + ((u >> 16) & 1u)) >> 16;   // round-nearest-even
    return (u16)r;
}
__device__ __forceinline__ float bf2f(u16 b) {
    union { unsigned int u; float f; } v; v.u = ((unsigned int)b) << 16;
    return v.f;
}

// ------- Kernel 1: grid-fused pre-pass --------------------------------------------
// Blocks [0, MROWS): degree + adj bitmask + gate  (xg = bf16(x * sig(deg*Wd+bd)))
// Blocks [MROWS, MROWS+768): W transpose+pack     (Wt[n][k] = bf16(W[k][n]))
__global__ __launch_bounds__(256) void pre_kernel(const float* __restrict__ adj,
                                                  const float* __restrict__ x,
                                                  const float* __restrict__ Wd,
                                                  const float* __restrict__ bd,
                                                  const float* __restrict__ W,
                                                  u16* __restrict__ xg,
                                                  u64* __restrict__ adjbits,
                                                  u16* __restrict__ Wt) {
    __shared__ float wsum[4];
    __shared__ float tile[64][65];
    int t = threadIdx.x;
    if (blockIdx.x < MROWS) {
        int row = blockIdx.x;
        int w = t >> 6, lane = t & 63;
        const float* a = adj + (size_t)row * LDIM;
        float v0 = a[w * 128 + lane];
        float v1 = a[w * 128 + 64 + lane];
        u64 b0 = __ballot(v0 != 0.f);
        u64 b1 = __ballot(v1 != 0.f);
        if (lane == 0) {
            adjbits[(size_t)row * (LDIM / 64) + 2 * w]     = b0;
            adjbits[(size_t)row * (LDIM / 64) + 2 * w + 1] = b1;
        }
        float s = v0 + v1;
        #pragma unroll
        for (int off = 32; off > 0; off >>= 1) s += __shfl_down(s, off);
        if (lane == 0) wsum[w] = s;
        __syncthreads();
        float d = wsum[0] + wsum[1] + wsum[2] + wsum[3];

        float4 xv = ((const float4*)(x + (size_t)row * CDIM))[t];
        float4 wv = ((const float4*)Wd)[t];
        float4 bv = ((const float4*)bd)[t];
        s4v o;
        o.x = (short)f2bf(xv.x * sigmoidf_(d * wv.x + bv.x));
        o.y = (short)f2bf(xv.y * sigmoidf_(d * wv.y + bv.y));
        o.z = (short)f2bf(xv.z * sigmoidf_(d * wv.z + bv.z));
        o.w = (short)f2bf(xv.w * sigmoidf_(d * wv.w + bv.w));
        ((s4v*)(xg + (size_t)row * CDIM))[t] = o;
    } else {
        int bid = blockIdx.x - MROWS;                 // 0..767
        int k0 = (bid & 15) * 64, n0 = (bid >> 4) * 64;
        int tx = t & 63, ty = t >> 6;                 // ty 0..3
        #pragma unroll
        for (int yy = ty; yy < 64; yy += 4)
            tile[yy][tx] = W[(size_t)(k0 + yy) * N3 + n0 + tx];
        __syncthreads();
        #pragma unroll
        for (int yy = ty; yy < 64; yy += 4)
            Wt[(size_t)(n0 + yy) * CDIM + k0 + tx] = f2bf(tile[tx][yy]);
    }
}

// ---------------- Kernel 2: bf16 MFMA GEMM (m97-style), fused chunk epilogue --------
// qkv = xg @ W + b : M=8192, N=3072, K=1024. A=[M][K] bf16, Bt=[N][K] bf16.
// global_load_lds width=16 into XOR-swizzled LDS; frag reads 2 lanes/bank (free).
// chunk 0 (qk):  sigmoid -> ksig bf16 [B,H,L,HD]
// chunk 1 (res): bf16 [B,L,C]
// chunk 2 (val): bf16 transposed -> vt [B,H,HD,L]
__global__ __launch_bounds__(256, 3) void gemm_bf16_kernel(const u16* __restrict__ A,
                                                           const u16* __restrict__ Bt,
                                                           const float* __restrict__ bias,
                                                           u16* __restrict__ ksig,
                                                           u16* __restrict__ resb,
                                                           u16* __restrict__ vt) {
    __shared__ __align__(16) u16 As[128 * 64];   // swizzled 16B slots: slot = row*8 + (seg^(row&7))
    __shared__ __align__(16) u16 Bs[128 * 64];
    int t = threadIdx.x;
    int m0 = blockIdx.y * 128, n0 = blockIdx.x * 128;
    int lane = t & 63, w = t >> 6;
    int i15 = lane & 15, quad = lane >> 4;
    int wm = w >> 1, wn = w & 1;

    f32x4 acc[4][4];
    #pragma unroll
    for (int i = 0; i < 4; ++i)
        #pragma unroll
        for (int j = 0; j < 4; ++j) acc[i][j] = (f32x4)(0.f);

    for (int k0 = 0; k0 < CDIM; k0 += 64) {
        #pragma unroll
        for (int p = 0; p < 4; ++p) {
            int sb = (w * 4 + p) * 64;           // wave-uniform slot base
            int s = sb + lane;
            int row = s >> 3;
            int seg = (s & 7) ^ (row & 7);       // global-side XOR swizzle
            const u16* ga = A + (size_t)(m0 + row) * CDIM + k0 + seg * 8;
            const u16* gb = Bt + (size_t)(n0 + row) * CDIM + k0 + seg * 8;
            __builtin_amdgcn_global_load_lds(
                (const __attribute__((address_space(1))) unsigned int*)ga,
                (__attribute__((address_space(3))) unsigned int*)&As[sb * 8], 16, 0, 0);
            __builtin_amdgcn_global_load_lds(
                (const __attribute__((address_space(1))) unsigned int*)gb,
                (__attribute__((address_space(3))) unsigned int*)&Bs[sb * 8], 16, 0, 0);
        }
        __syncthreads();
        #pragma unroll
        for (int kc = 0; kc < 2; ++kc) {
            s8v aF[4], bF[4];
            #pragma unroll
            for (int mt = 0; mt < 4; ++mt) {
                int row = wm * 64 + mt * 16 + i15;
                int slot = row * 8 + ((kc * 4 + quad) ^ (i15 & 7));
                aF[mt] = *(const s8v*)&As[slot * 8];
            }
            #pragma unroll
            for (int nt = 0; nt < 4; ++nt) {
                int row = wn * 64 + nt * 16 + i15;
                int slot = row * 8 + ((kc * 4 + quad) ^ (i15 & 7));
                bF[nt] = *(const s8v*)&Bs[slot * 8];
            }
            #pragma unroll
            for (int mt = 0; mt < 4; ++mt)
                #pragma unroll
                for (int nt = 0; nt < 4; ++nt)
                    acc[mt][nt] = __builtin_amdgcn_mfma_f32_16x16x32_bf16(aF[mt], bF[nt], acc[mt][nt], 0, 0, 0);
        }
        __syncthreads();
    }

    int chunk = n0 >> 10;
    #pragma unroll
    for (int nt = 0; nt < 4; ++nt) {
        int ncol = n0 + wn * 64 + nt * 16 + i15;
        float bv = bias[ncol];
        #pragma unroll
        for (int mt = 0; mt < 4; ++mt) {
            int mbase = m0 + wm * 64 + mt * 16 + quad * 4;
            if (chunk == 0) {
                int h = (ncol >> 7) & 7, d = ncol & 127;
                #pragma unroll
                for (int r = 0; r < 4; ++r) {
                    int mrow = mbase + r;
                    int bb = mrow >> 9, l = mrow & 511;
                    ksig[(((size_t)bb * NH + h) * LDIM + l) * HD + d] = f2bf(sigmoidf_(acc[mt][nt][r] + bv));
                }
            } else if (chunk == 1) {
                #pragma unroll
                for (int r = 0; r < 4; ++r) {
                    int mrow = mbase + r;
                    resb[(size_t)mrow * CDIM + (ncol - CDIM)] = f2bf(acc[mt][nt][r] + bv);
                }
            } else {
                int h = (ncol >> 7) & 7, d = ncol & 127;
                int bb = mbase >> 9, l = mbase & 511;   // 4 consecutive l, no 512-wrap (mbase%4==0)
                s4v pk;
                pk.x = (short)f2bf(acc[mt][nt][0] + bv);
                pk.y = (short)f2bf(acc[mt][nt][1] + bv);
                pk.z = (short)f2bf(acc[mt][nt][2] + bv);
                pk.w = (short)f2bf(acc[mt][nt][3] + bv);
                *(s4v*)&vt[(((size_t)bb * NH + h) * HD + d) * LDIM + l] = pk;
            }
        }
    }
}

// ---------------- Kernel 3: BARRIER-FREE fused MFMA attention ----------------------
// Grid id = l*128 + b*8 + h (id%8 == h: XCD locality), 1024 blocks x 4 waves.
// Each wave is fully independent: 16 l-rows; K/V fragments loaded DIRECTLY from
// global into VGPRs (B-frag layout == row-major b128 loads, coalesced per quad-group;
// 4x redundancy across waves absorbed by L1/L2). Only LDS use: per-wave P C->A
// layout round-trip (disjoint slices, in-wave lgkmcnt ordering, NO __syncthreads).
// O_unnorm += P.V, rowsum += sum(P); divide once at the end (linear norm).
__global__ __launch_bounds__(256, 4) void attn_kernel(const u16* __restrict__ ksig,
                                                      const u16* __restrict__ vt,
                                                      const u16* __restrict__ resb,
                                                      const u64* __restrict__ adjbits,
                                                      float* __restrict__ out) {
    __shared__ __align__(16) u16 lds_ps[4][16][72]; // per-wave P tile [l][m], 64 + 8 pad

    int t = threadIdx.x;
    int lane = t & 63, w = t >> 6;
    int i15 = lane & 15, quad = lane >> 4;
    int bid = blockIdx.x;
    int l0 = (bid >> 7) * 64;
    int b  = (bid >> 3) & 15;
    int h  = bid & 7;

    const u16* ksig_bh = ksig + ((size_t)b * NH + h) * LDIM * HD;
    const u16* vt_bh   = vt + ((size_t)b * NH + h) * HD * LDIM;
    const u64* abits   = adjbits + ((size_t)b * LDIM + l0 + w * 16 + quad * 4) * (LDIM / 64);

    // Q A-frags from global (sigmoid pre-applied in GEMM epilogue)
    s8v aQ[4];
    {
        const u16* qrow = ksig_bh + (size_t)(l0 + w * 16 + i15) * HD + quad * 8;
        #pragma unroll
        for (int kc = 0; kc < 4; ++kc) aQ[kc] = *(const s8v*)(qrow + kc * 32);
    }

    f32x4 accO[8];
    #pragma unroll
    for (int i = 0; i < 8; ++i) accO[i] = (f32x4)(0.f);
    float prs[4] = {0.f, 0.f, 0.f, 0.f};

    const float scale = 0.08838834764831845f;  // 1/sqrt(128)

    for (int m0 = 0; m0 < LDIM; m0 += 64) {
        // --- adj mask words (broadcast loads; consumed after S) ---
        unsigned int mw0[4], mw1[4];
        #pragma unroll
        for (int r = 0; r < 4; ++r) {
            u64 wrd = abits[(size_t)r * (LDIM / 64) + (m0 >> 6)];
            mw0[r] = (unsigned int)wrd;
            mw1[r] = (unsigned int)(wrd >> 32);
        }

        // --- S = sig(Q) sig(K)^T : bK frags direct from global (b128/lane) ---
        f32x4 S[4];
        #pragma unroll
        for (int nt = 0; nt < 4; ++nt) {
            S[nt] = (f32x4)(0.f);
            const u16* krow = ksig_bh + (size_t)(m0 + nt * 16 + i15) * HD + quad * 8;
            #pragma unroll
            for (int kc = 0; kc < 4; ++kc) {
                s8v bK = *(const s8v*)(krow + kc * 32);
                S[nt] = __builtin_amdgcn_mfma_f32_16x16x32_bf16(aQ[kc], bK, S[nt], 0, 0, 0);
            }
        }

        // --- mask via bit-test, rowsum, P -> per-wave LDS slice (no barrier) ---
        #pragma unroll
        for (int nt = 0; nt < 4; ++nt) {
            int sh = (nt & 1) * 16 + i15;
            #pragma unroll
            for (int r = 0; r < 4; ++r) {
                unsigned int half = (nt < 2) ? mw0[r] : mw1[r];
                float p = ((half >> sh) & 1u) ? S[nt][r] * scale : 0.f;
                prs[r] += p;
                lds_ps[w][quad * 4 + r][nt * 16 + i15] = f2bf(p);
            }
        }

        // --- O += P . V : bV frags direct from global (vt is [d][l]) ---
        {
            s8v aP[2];
            #pragma unroll
            for (int ks = 0; ks < 2; ++ks)
                aP[ks] = *(const s8v*)&lds_ps[w][i15][ks * 32 + quad * 8];
            #pragma unroll
            for (int ntd = 0; ntd < 8; ++ntd) {
                const u16* vrow = vt_bh + (size_t)(ntd * 16 + i15) * LDIM + m0 + quad * 8;
                #pragma unroll
                for (int ks = 0; ks < 2; ++ks) {
                    s8v bV = *(const s8v*)(vrow + ks * 32);
                    accO[ntd] = __builtin_amdgcn_mfma_f32_16x16x32_bf16(aP[ks], bV, accO[ntd], 0, 0, 0);
                }
            }
        }
    }

    // --- epilogue: reduce rowsums across the 16 key-lanes, normalize, +res, relu ---
    float inv[4];
    #pragma unroll
    for (int r = 0; r < 4; ++r) {
        float s = prs[r];
        s += __shfl_xor(s, 1);
        s += __shfl_xor(s, 2);
        s += __shfl_xor(s, 4);
        s += __shfl_xor(s, 8);
        inv[r] = 1.0f / (s + 1e-6f);
    }
    #pragma unroll
    for (int ntd = 0; ntd < 8; ++ntd) {
        int dcol = h * HD + ntd * 16 + i15;
        #pragma unroll
        for (int r = 0; r < 4; ++r) {
            size_t idx = ((size_t)b * LDIM + l0 + w * 16 + quad * 4 + r) * CDIM + dcol;
            float v = accO[ntd][r] * inv[r] + bf2f(resb[idx]);
            out[idx] = fmaxf(v, 0.f);
        }
    }
}

// ---------------- launch ----------------
extern "C" void kernel_launch(void* const* d_in, const int* in_sizes, int n_in,
                              void* d_out, int out_size, void* d_ws, size_t ws_size,
                              hipStream_t stream) {
    (void)in_sizes; (void)n_in; (void)out_size; (void)ws_size;
    const float* x     = (const float*)d_in[0];
    const float* adj   = (const float*)d_in[1];
    const float* W_qkv = (const float*)d_in[2];
    const float* b_qkv = (const float*)d_in[3];
    const float* W_d   = (const float*)d_in[4];
    const float* b_d   = (const float*)d_in[5];
    float* out = (float*)d_out;

    char* ws = (char*)d_ws;
    size_t off = 0;
    u64* adjb   = (u64*)(ws + off);   off += (size_t)MROWS * 8 * 8;       // 512 KB
    u16*   xg   = (u16*)(ws + off);   off += (size_t)MROWS * CDIM * 2;    // 16 MB
    u16*   Wt   = (u16*)(ws + off);   off += (size_t)N3 * CDIM * 2;       // 6 MB
    u16*   ksig = (u16*)(ws + off);   off += (size_t)MROWS * CDIM * 2;    // 16 MB
    u16*   resb = (u16*)(ws + off);   off += (size_t)MROWS * CDIM * 2;    // 16 MB
    u16*   vt   = (u16*)(ws + off);   off += (size_t)MROWS * CDIM * 2;    // 16 MB

    pre_kernel<<<MROWS + (CDIM / 64) * (N3 / 64), 256, 0, stream>>>(adj, x, W_d, b_d, W_qkv, xg, adjb, Wt);
    gemm_bf16_kernel<<<dim3(N3 / 128, MROWS / 128), 256, 0, stream>>>(xg, Wt, b_qkv, ksig, resb, vt);
    attn_kernel<<<LDIM / 64 * NH * BDIM, 256, 0, stream>>>(ksig, vt, resb, adjb, out);
}

// Round 8
// 212.154 us; speedup vs baseline: 1.4033x; 1.4033x over previous
//
#include <hip/hip_runtime.h>
#include <math.h>

#define BDIM 16
#define LDIM 512
#define CDIM 1024
#define NH 8
#define HD 128
#define MROWS (BDIM * LDIM)   /* 8192 */
#define N3 (3 * CDIM)         /* 3072 */

typedef unsigned short u16;
typedef unsigned long long u64;
typedef short s8v __attribute__((ext_vector_type(8)));   // 8 bf16 = 4 VGPRs (MFMA A/B frag)
typedef short s4v __attribute__((ext_vector_type(4)));   // 4 bf16 = 2 VGPRs
typedef float f32x4 __attribute__((ext_vector_type(4))); // MFMA C/D frag

__device__ __forceinline__ float sigmoidf_(float z) {
    return 1.0f / (1.0f + __expf(-z));
}
__device__ __forceinline__ u16 f2bf(float f) {
    union { float f; unsigned int u; } v; v.f = f;
    unsigned int u = v.u;
    unsigned int r = (u + 0x7FFFu + ((u >> 16) & 1u)) >> 16;   // round-nearest-even
    return (u16)r;
}
__device__ __forceinline__ float bf2f(u16 b) {
    union { unsigned int u; float f; } v; v.u = ((unsigned int)b) << 16;
    return v.f;
}

// ------- Kernel 1: grid-fused pre-pass --------------------------------------------
// Blocks [0, MROWS): degree + adj bitmask + gate  (xg = bf16(x * sig(deg*Wd+bd)))
// Blocks [MROWS, MROWS+768): W transpose+pack     (Wt[n][k] = bf16(W[k][n]))
__global__ __launch_bounds__(256) void pre_kernel(const float* __restrict__ adj,
                                                  const float* __restrict__ x,
                                                  const float* __restrict__ Wd,
                                                  const float* __restrict__ bd,
                                                  const float* __restrict__ W,
                                                  u16* __restrict__ xg,
                                                  u64* __restrict__ adjbits,
                                                  u16* __restrict__ Wt) {
    __shared__ float wsum[4];
    __shared__ float tile[64][65];
    int t = threadIdx.x;
    if (blockIdx.x < MROWS) {
        int row = blockIdx.x;
        int w = t >> 6, lane = t & 63;
        const float* a = adj + (size_t)row * LDIM;
        float v0 = a[w * 128 + lane];
        float v1 = a[w * 128 + 64 + lane];
        u64 b0 = __ballot(v0 != 0.f);
        u64 b1 = __ballot(v1 != 0.f);
        if (lane == 0) {
            adjbits[(size_t)row * (LDIM / 64) + 2 * w]     = b0;
            adjbits[(size_t)row * (LDIM / 64) + 2 * w + 1] = b1;
        }
        float s = v0 + v1;
        #pragma unroll
        for (int off = 32; off > 0; off >>= 1) s += __shfl_down(s, off);
        if (lane == 0) wsum[w] = s;
        __syncthreads();
        float d = wsum[0] + wsum[1] + wsum[2] + wsum[3];

        float4 xv = ((const float4*)(x + (size_t)row * CDIM))[t];
        float4 wv = ((const float4*)Wd)[t];
        float4 bv = ((const float4*)bd)[t];
        s4v o;
        o.x = (short)f2bf(xv.x * sigmoidf_(d * wv.x + bv.x));
        o.y = (short)f2bf(xv.y * sigmoidf_(d * wv.y + bv.y));
        o.z = (short)f2bf(xv.z * sigmoidf_(d * wv.z + bv.z));
        o.w = (short)f2bf(xv.w * sigmoidf_(d * wv.w + bv.w));
        ((s4v*)(xg + (size_t)row * CDIM))[t] = o;
    } else {
        int bid = blockIdx.x - MROWS;                 // 0..767
        int k0 = (bid & 15) * 64, n0 = (bid >> 4) * 64;
        int tx = t & 63, ty = t >> 6;                 // ty 0..3
        #pragma unroll
        for (int yy = ty; yy < 64; yy += 4)
            tile[yy][tx] = W[(size_t)(k0 + yy) * N3 + n0 + tx];
        __syncthreads();
        #pragma unroll
        for (int yy = ty; yy < 64; yy += 4)
            Wt[(size_t)(n0 + yy) * CDIM + k0 + tx] = f2bf(tile[tx][yy]);
    }
}

// ---------------- Kernel 2: bf16 MFMA GEMM (m97-style), fused chunk epilogue --------
// qkv = xg @ W + b : M=8192, N=3072, K=1024. A=[M][K] bf16, Bt=[N][K] bf16.
// global_load_lds width=16 into XOR-swizzled LDS; frag reads 2 lanes/bank (free).
// chunk 0 (qk):  sigmoid -> ksig bf16 [B,H,L,HD]
// chunk 1 (res): bf16 [B,L,C]
// chunk 2 (val): bf16 transposed -> vt [B,H,HD,L]
__global__ __launch_bounds__(256, 3) void gemm_bf16_kernel(const u16* __restrict__ A,
                                                           const u16* __restrict__ Bt,
                                                           const float* __restrict__ bias,
                                                           u16* __restrict__ ksig,
                                                           u16* __restrict__ resb,
                                                           u16* __restrict__ vt) {
    __shared__ __align__(16) u16 As[128 * 64];   // swizzled 16B slots: slot = row*8 + (seg^(row&7))
    __shared__ __align__(16) u16 Bs[128 * 64];
    int t = threadIdx.x;
    int m0 = blockIdx.y * 128, n0 = blockIdx.x * 128;
    int lane = t & 63, w = t >> 6;
    int i15 = lane & 15, quad = lane >> 4;
    int wm = w >> 1, wn = w & 1;

    f32x4 acc[4][4];
    #pragma unroll
    for (int i = 0; i < 4; ++i)
        #pragma unroll
        for (int j = 0; j < 4; ++j) acc[i][j] = (f32x4)(0.f);

    for (int k0 = 0; k0 < CDIM; k0 += 64) {
        #pragma unroll
        for (int p = 0; p < 4; ++p) {
            int sb = (w * 4 + p) * 64;           // wave-uniform slot base
            int s = sb + lane;
            int row = s >> 3;
            int seg = (s & 7) ^ (row & 7);       // global-side XOR swizzle
            const u16* ga = A + (size_t)(m0 + row) * CDIM + k0 + seg * 8;
            const u16* gb = Bt + (size_t)(n0 + row) * CDIM + k0 + seg * 8;
            __builtin_amdgcn_global_load_lds(
                (const __attribute__((address_space(1))) unsigned int*)ga,
                (__attribute__((address_space(3))) unsigned int*)&As[sb * 8], 16, 0, 0);
            __builtin_amdgcn_global_load_lds(
                (const __attribute__((address_space(1))) unsigned int*)gb,
                (__attribute__((address_space(3))) unsigned int*)&Bs[sb * 8], 16, 0, 0);
        }
        __syncthreads();
        #pragma unroll
        for (int kc = 0; kc < 2; ++kc) {
            s8v aF[4], bF[4];
            #pragma unroll
            for (int mt = 0; mt < 4; ++mt) {
                int row = wm * 64 + mt * 16 + i15;
                int slot = row * 8 + ((kc * 4 + quad) ^ (i15 & 7));
                aF[mt] = *(const s8v*)&As[slot * 8];
            }
            #pragma unroll
            for (int nt = 0; nt < 4; ++nt) {
                int row = wn * 64 + nt * 16 + i15;
                int slot = row * 8 + ((kc * 4 + quad) ^ (i15 & 7));
                bF[nt] = *(const s8v*)&Bs[slot * 8];
            }
            #pragma unroll
            for (int mt = 0; mt < 4; ++mt)
                #pragma unroll
                for (int nt = 0; nt < 4; ++nt)
                    acc[mt][nt] = __builtin_amdgcn_mfma_f32_16x16x32_bf16(aF[mt], bF[nt], acc[mt][nt], 0, 0, 0);
        }
        __syncthreads();
    }

    int chunk = n0 >> 10;
    #pragma unroll
    for (int nt = 0; nt < 4; ++nt) {
        int ncol = n0 + wn * 64 + nt * 16 + i15;
        float bv = bias[ncol];
        #pragma unroll
        for (int mt = 0; mt < 4; ++mt) {
            int mbase = m0 + wm * 64 + mt * 16 + quad * 4;
            if (chunk == 0) {
                int h = (ncol >> 7) & 7, d = ncol & 127;
                #pragma unroll
                for (int r = 0; r < 4; ++r) {
                    int mrow = mbase + r;
                    int bb = mrow >> 9, l = mrow & 511;
                    ksig[(((size_t)bb * NH + h) * LDIM + l) * HD + d] = f2bf(sigmoidf_(acc[mt][nt][r] + bv));
                }
            } else if (chunk == 1) {
                #pragma unroll
                for (int r = 0; r < 4; ++r) {
                    int mrow = mbase + r;
                    resb[(size_t)mrow * CDIM + (ncol - CDIM)] = f2bf(acc[mt][nt][r] + bv);
                }
            } else {
                int h = (ncol >> 7) & 7, d = ncol & 127;
                int bb = mbase >> 9, l = mbase & 511;   // 4 consecutive l, no 512-wrap (mbase%4==0)
                s4v pk;
                pk.x = (short)f2bf(acc[mt][nt][0] + bv);
                pk.y = (short)f2bf(acc[mt][nt][1] + bv);
                pk.z = (short)f2bf(acc[mt][nt][2] + bv);
                pk.w = (short)f2bf(acc[mt][nt][3] + bv);
                *(s4v*)&vt[(((size_t)bb * NH + h) * HD + d) * LDIM + l] = pk;
            }
        }
    }
}

// ---------------- Kernel 3: fused MFMA attention, double-buffered DMA ---------------
// Grid id = l*128 + b*8 + h (id%8 == h: XCD locality), 1024 blocks x 4 waves x 16 l.
// m-tiles of 32 keys, double-buffered: issue DMA(i+1) -> compute(i) -> one barrier.
// The vmcnt(0) drain at the barrier is overlapped by the whole compute phase.
// O_unnorm += P.V, rowsum += sum(P); divide once at the end (linear norm).
#define MT 32
#define NITER (LDIM / MT)
__global__ __launch_bounds__(256) void attn_kernel(const u16* __restrict__ ksig,
                                                   const u16* __restrict__ vt,
                                                   const u16* __restrict__ resb,
                                                   const u64* __restrict__ adjbits,
                                                   float* __restrict__ out) {
    __shared__ __align__(16) u16 lds_ks[2][MT * 128];  // K tile, swizzled: slot=row*16+(seg^(row&15))
    __shared__ __align__(16) u16 lds_vt[2][128 * MT];  // V^T tile, swizzled: slot=row*4+(seg^((row>>1)&3))
    __shared__ __align__(16) u16 lds_ps[4][16][40];    // per-wave P tile [l][m], 32 + 8 pad

    int t = threadIdx.x;
    int lane = t & 63, w = t >> 6;
    int i15 = lane & 15, quad = lane >> 4;
    int bid = blockIdx.x;
    int l0 = (bid >> 7) * 64;
    int b  = (bid >> 3) & 15;
    int h  = bid & 7;

    const u16* ksig_bh = ksig + ((size_t)b * NH + h) * LDIM * HD;
    const u16* vt_bh   = vt + ((size_t)b * NH + h) * HD * LDIM;
    const unsigned int* abits32 = (const unsigned int*)adjbits;
    size_t arow0 = ((size_t)b * LDIM + l0 + w * 16 + quad * 4) * (LDIM / 32);

    // Q A-frags from global (sigmoid pre-applied in GEMM epilogue)
    s8v aQ[4];
    {
        const u16* qrow = ksig_bh + (size_t)(l0 + w * 16 + i15) * HD + quad * 8;
        #pragma unroll
        for (int kc = 0; kc < 4; ++kc) aQ[kc] = *(const s8v*)(qrow + kc * 32);
    }

    f32x4 accO[8];
    #pragma unroll
    for (int i = 0; i < 8; ++i) accO[i] = (f32x4)(0.f);
    float prs[4] = {0.f, 0.f, 0.f, 0.f};

    const float scale = 0.08838834764831845f;  // 1/sqrt(128)

    // --- staging: K tile 32x128 (512 slots, 2 DMA/thread), V^T 128x32 (512, 2/thread)
    auto stage = [&](int m0s, int buf) {
        #pragma unroll
        for (int p = 0; p < 2; ++p) {
            int sb = (w * 2 + p) * 64;
            int s = sb + lane;
            int row = s >> 4;
            int seg = (s & 15) ^ (row & 15);
            const u16* g = ksig_bh + (size_t)(m0s + row) * HD + seg * 8;
            __builtin_amdgcn_global_load_lds(
                (const __attribute__((address_space(1))) unsigned int*)g,
                (__attribute__((address_space(3))) unsigned int*)&lds_ks[buf][sb * 8], 16, 0, 0);
        }
        #pragma unroll
        for (int p = 0; p < 2; ++p) {
            int sb = (w * 2 + p) * 64;
            int s = sb + lane;
            int row = s >> 2;
            int seg = (s & 3) ^ ((row >> 1) & 3);
            const u16* g = vt_bh + (size_t)row * LDIM + m0s + seg * 8;
            __builtin_amdgcn_global_load_lds(
                (const __attribute__((address_space(1))) unsigned int*)g,
                (__attribute__((address_space(3))) unsigned int*)&lds_vt[buf][sb * 8], 16, 0, 0);
        }
    };

    stage(0, 0);
    __syncthreads();

    for (int i = 0; i < NITER; ++i) {
        int cur = i & 1;
        int m0 = i * MT;
        if (i + 1 < NITER) stage(m0 + MT, cur ^ 1);   // prefetch overlaps compute below

        // adj mask words (u32 = 32 keys), broadcast loads
        unsigned int mw[4];
        #pragma unroll
        for (int r = 0; r < 4; ++r)
            mw[r] = abits32[arow0 + (size_t)r * (LDIM / 32) + i];

        // --- S = sig(Q) sig(K)^T : 2 key-tiles x 4 k-steps ---
        f32x4 S[2];
        #pragma unroll
        for (int nt = 0; nt < 2; ++nt) {
            S[nt] = (f32x4)(0.f);
            int row = nt * 16 + i15;
            #pragma unroll
            for (int kc = 0; kc < 4; ++kc) {
                int slot = row * 16 + ((kc * 4 + quad) ^ (row & 15));
                s8v bK = *(const s8v*)&lds_ks[cur][slot * 8];
                S[nt] = __builtin_amdgcn_mfma_f32_16x16x32_bf16(aQ[kc], bK, S[nt], 0, 0, 0);
            }
        }

        // --- mask via bit-test, rowsum, P -> per-wave LDS slice (in-wave order) ---
        #pragma unroll
        for (int nt = 0; nt < 2; ++nt) {
            int sh = nt * 16 + i15;
            #pragma unroll
            for (int r = 0; r < 4; ++r) {
                float p = ((mw[r] >> sh) & 1u) ? S[nt][r] * scale : 0.f;
                prs[r] += p;
                lds_ps[w][quad * 4 + r][nt * 16 + i15] = f2bf(p);
            }
        }

        // --- O += P . V (single 32-wide k-step) ---
        {
            s8v aP = *(const s8v*)&lds_ps[w][i15][quad * 8];
            #pragma unroll
            for (int ntd = 0; ntd < 8; ++ntd) {
                int row = ntd * 16 + i15;
                int slot = row * 4 + (quad ^ ((row >> 1) & 3));
                s8v bV = *(const s8v*)&lds_vt[cur][slot * 8];
                accO[ntd] = __builtin_amdgcn_mfma_f32_16x16x32_bf16(aP, bV, accO[ntd], 0, 0, 0);
            }
        }
        if (i + 1 < NITER) __syncthreads();   // drains prefetch (already overlapped) + buf swap
    }

    // --- epilogue: reduce rowsums across the 16 key-lanes, normalize, +res, relu ---
    float inv[4];
    #pragma unroll
    for (int r = 0; r < 4; ++r) {
        float s = prs[r];
        s += __shfl_xor(s, 1);
        s += __shfl_xor(s, 2);
        s += __shfl_xor(s, 4);
        s += __shfl_xor(s, 8);
        inv[r] = 1.0f / (s + 1e-6f);
    }
    #pragma unroll
    for (int ntd = 0; ntd < 8; ++ntd) {
        int dcol = h * HD + ntd * 16 + i15;
        #pragma unroll
        for (int r = 0; r < 4; ++r) {
            size_t idx = ((size_t)b * LDIM + l0 + w * 16 + quad * 4 + r) * CDIM + dcol;
            float v = accO[ntd][r] * inv[r] + bf2f(resb[idx]);
            out[idx] = fmaxf(v, 0.f);
        }
    }
}

// ---------------- launch ----------------
extern "C" void kernel_launch(void* const* d_in, const int* in_sizes, int n_in,
                              void* d_out, int out_size, void* d_ws, size_t ws_size,
                              hipStream_t stream) {
    (void)in_sizes; (void)n_in; (void)out_size; (void)ws_size;
    const float* x     = (const float*)d_in[0];
    const float* adj   = (const float*)d_in[1];
    const float* W_qkv = (const float*)d_in[2];
    const float* b_qkv = (const float*)d_in[3];
    const float* W_d   = (const float*)d_in[4];
    const float* b_d   = (const float*)d_in[5];
    float* out = (float*)d_out;

    char* ws = (char*)d_ws;
    size_t off = 0;
    u64* adjb   = (u64*)(ws + off);   off += (size_t)MROWS * 8 * 8;       // 512 KB
    u16*   xg   = (u16*)(ws + off);   off += (size_t)MROWS * CDIM * 2;    // 16 MB
    u16*   Wt   = (u16*)(ws + off);   off += (size_t)N3 * CDIM * 2;       // 6 MB
    u16*   ksig = (u16*)(ws + off);   off += (size_t)MROWS * CDIM * 2;    // 16 MB
    u16*   resb = (u16*)(ws + off);   off += (size_t)MROWS * CDIM * 2;    // 16 MB
    u16*   vt   = (u16*)(ws + off);   off += (size_t)MROWS * CDIM * 2;    // 16 MB

    pre_kernel<<<MROWS + (CDIM / 64) * (N3 / 64), 256, 0, stream>>>(adj, x, W_d, b_d, W_qkv, xg, adjb, Wt);
    gemm_bf16_kernel<<<dim3(N3 / 128, MROWS / 128), 256, 0, stream>>>(xg, Wt, b_qkv, ksig, resb, vt);
    attn_kernel<<<LDIM / 64 * NH * BDIM, 256, 0, stream>>>(ksig, vt, resb, adjb, out);
}